// Round 9
// baseline (641.273 us; speedup 1.0000x reference)
//
#include <hip/hip_runtime.h>
#include <hip/hip_bf16.h>

typedef float f32x4 __attribute__((ext_vector_type(4)));
typedef int i32x4v __attribute__((ext_vector_type(4)));
typedef int i32x8v __attribute__((ext_vector_type(8)));

#define IGNORE_INDEX (-100)
#define N_ROWS 4096
#define H_DIM  1024
#define V_DIM  32000

#define BM 256
#define BN 256
#define BK 128                 /* fp8 elements = bytes */
#define CT_NUM (V_DIM / BN)    /* 125 */
#define RT_NUM (N_ROWS / BM)   /* 16 */
#define SCALE1 0x7f7f7f7f      /* 4x e8m0 = 127 -> x1.0 */

// ---------- fused prep: cast x -> fp8 (blocks < XB8) + transpose-cast w ----------
#define XB8 (N_ROWS * H_DIM / (256 * 16))  /* 1024 */
__global__ __launch_bounds__(256) void k_prep(const float* __restrict__ x,
                                              const float* __restrict__ w,
                                              unsigned char* __restrict__ x8,
                                              unsigned char* __restrict__ wT8) {
  __shared__ float tile[128][65];
  const int t = threadIdx.x;
  if (blockIdx.x < XB8) {
    size_t i = ((size_t)blockIdx.x * 256 + t) * 16;
    const float4* xp = (const float4*)(x + i);
    float4 f0 = xp[0], f1 = xp[1], f2 = xp[2], f3 = xp[3];
    int4 o;
    int r;
    r = __builtin_amdgcn_cvt_pk_fp8_f32(f0.x, f0.y, 0, false);
    r = __builtin_amdgcn_cvt_pk_fp8_f32(f0.z, f0.w, r, true);
    o.x = r;
    r = __builtin_amdgcn_cvt_pk_fp8_f32(f1.x, f1.y, 0, false);
    r = __builtin_amdgcn_cvt_pk_fp8_f32(f1.z, f1.w, r, true);
    o.y = r;
    r = __builtin_amdgcn_cvt_pk_fp8_f32(f2.x, f2.y, 0, false);
    r = __builtin_amdgcn_cvt_pk_fp8_f32(f2.z, f2.w, r, true);
    o.z = r;
    r = __builtin_amdgcn_cvt_pk_fp8_f32(f3.x, f3.y, 0, false);
    r = __builtin_amdgcn_cvt_pk_fp8_f32(f3.z, f3.w, r, true);
    o.w = r;
    *(int4*)(x8 + i) = o;
    return;
  }
  const int b = blockIdx.x - XB8;
  const int v0 = (b % (V_DIM / 64)) * 64;
  const int k0 = (b / (V_DIM / 64)) * 128;
  {
    const int vq = t & 15;    // float4 index (16 x 4 = 64 floats/row)
    const int kr = t >> 4;    // 0..15
#pragma unroll
    for (int p = 0; p < 128; p += 16) {
      float4 v = *(const float4*)(w + (size_t)(k0 + kr + p) * V_DIM + v0 + vq * 4);
      tile[kr + p][vq * 4 + 0] = v.x;
      tile[kr + p][vq * 4 + 1] = v.y;
      tile[kr + p][vq * 4 + 2] = v.z;
      tile[kr + p][vq * 4 + 3] = v.w;
    }
  }
  __syncthreads();
  {
    const int vr = t >> 2;    // 0..63
    const int kq2 = t & 3;
#pragma unroll
    for (int h = 0; h < 2; ++h) {
      const int d4 = kq2 + h * 4;   // int4 index within 128B k-run
      int4 o;
      int r;
#pragma unroll
      for (int d = 0; d < 4; ++d) {
        r = __builtin_amdgcn_cvt_pk_fp8_f32(tile[d4 * 16 + d * 4 + 0][vr],
                                            tile[d4 * 16 + d * 4 + 1][vr], 0, false);
        r = __builtin_amdgcn_cvt_pk_fp8_f32(tile[d4 * 16 + d * 4 + 2][vr],
                                            tile[d4 * 16 + d * 4 + 3][vr], r, true);
        ((int*)&o)[d] = r;
      }
      *(int4*)(wT8 + (size_t)(v0 + vr) * H_DIM + k0 + d4 * 16) = o;
    }
  }
}

// ---- fused MX-fp8 GEMM (256x256 tile, 8 waves, wave-tile 128x64) + lse ----
// Register budget (gfx950 unified VGPR/AGPR): 512 threads -> 1 block/CU ->
// 2 waves/SIMD -> 256 regs/wave. acc 8x4xf32x4=128 + a_frag[8]=64 + b_frag=8
// + addr ~15 => ~215 <= 256.  (R8's 16-wave version needed ~145 at a
// 128-reg budget -> spill. This config is the legal version of that trade.)
// bytes/MFMA: staged 64KB / 256 MFMA = 256 B (R7: 512 B).
// LDS reads/iter: 8 waves x 24 KB = 192 KB per 256 MFMA = 0.75 KB/MFMA.
// Aged prefetch dbuf: tile kt+1 issued right after barrier of iter kt.
__global__ __launch_bounds__(512, 2) void k_gemm_lse(const unsigned char* __restrict__ A,
                                                     const unsigned char* __restrict__ Bt,
                                                     float* __restrict__ m_part,
                                                     float* __restrict__ s_part) {
  __shared__ __align__(16) unsigned char sMem[2][2][BM * BK];  // [buf][A=0/B=1]
  float* maxbuf = (float*)&sMem[0][0][0];            // [BM][4], alias post-loop
  float* sumbuf = (float*)&sMem[0][0][4096];         // [BM][4]

  const int tid = threadIdx.x;
  const int rt = blockIdx.x;   // fast dim -> per-XCD A stays hot
  const int ct = blockIdx.y;
  const int m0 = rt * BM;
  const int n0 = ct * BN;

  const int w = tid >> 6;
  const int l = tid & 63;
  const int wr = w >> 2;       // 0..1 (128-row strip)
  const int wc = w & 3;        // 0..3 (64-col strip)
  const int quad = l >> 4, lc = l & 15;

  f32x4 acc[8][4];
#pragma unroll
  for (int i = 0; i < 8; ++i)
#pragma unroll
    for (int j = 0; j < 4; ++j)
      acc[i][j] = (f32x4){0.f, 0.f, 0.f, 0.f};

  // staging: 2048 slots per operand, 512 threads -> 4 issues each.
  // slot s = issue*512 + tid: row = s>>3, chunk-pos (s&7) = c ^ (row&7).
  const int srow = tid >> 3;                               // 0..63
  const int scol = ((tid & 7) ^ ((tid >> 3) & 7)) * 16;    // swizzled 16B chunk
  const unsigned char* ga = A + (size_t)(m0 + srow) * H_DIM + scol;
  const unsigned char* gb = Bt + (size_t)(n0 + srow) * H_DIM + scol;
  const int dOff = tid * 16;

  // fragment read offsets: lane (r15=lc, q=quad) reads chunks (2q)^(lc&7),
  // (2q+1)^(lc&7) of its row.
  const int base_r = lc * 128;
  const int sw0 = ((quad * 2) ^ (lc & 7)) * 16;
  const int sw1 = ((quad * 2 + 1) ^ (lc & 7)) * 16;

#define ISSUE_TILE(buf)                                                          \
  do {                                                                           \
    unsigned char* da_ = &sMem[buf][0][dOff];                                    \
    unsigned char* db_ = &sMem[buf][1][dOff];                                    \
    _Pragma("unroll")                                                            \
    for (int i_ = 0; i_ < 4; ++i_) {                                             \
      __builtin_amdgcn_global_load_lds(                                          \
          (const __attribute__((address_space(1))) void*)(ga + (size_t)i_ * 64 * H_DIM), \
          (__attribute__((address_space(3))) void*)(da_ + i_ * 8192), 16, 0, 0); \
      __builtin_amdgcn_global_load_lds(                                          \
          (const __attribute__((address_space(1))) void*)(gb + (size_t)i_ * 64 * H_DIM), \
          (__attribute__((address_space(3))) void*)(db_ + i_ * 8192), 16, 0, 0); \
    }                                                                            \
    ga += BK;                                                                    \
    gb += BK;                                                                    \
  } while (0)

  ISSUE_TILE(0);  // cold prologue load, tile 0

#pragma unroll
  for (int kt = 0; kt < H_DIM / BK; ++kt) {
    __syncthreads();  // drains tile-kt loads (aged 1 compute phase for kt>0);
                      // guarantees all waves done reading buf[(kt+1)&1]
    if (kt < H_DIM / BK - 1) ISSUE_TILE((kt + 1) & 1);

    const unsigned char* bufA = &sMem[kt & 1][0][0];
    const unsigned char* bufB = &sMem[kt & 1][1][0];
    i32x8v a_frag[8];
#pragma unroll
    for (int i = 0; i < 8; ++i) {
      const unsigned char* p = bufA + (wr * 8 + i) * 2048 + base_r;
      i32x4v lo = *(const i32x4v*)(p + sw0);
      i32x4v hi = *(const i32x4v*)(p + sw1);
      a_frag[i] = __builtin_shufflevector(lo, hi, 0, 1, 2, 3, 4, 5, 6, 7);
    }
#pragma unroll
    for (int j = 0; j < 4; ++j) {
      const unsigned char* p = bufB + (wc * 4 + j) * 2048 + base_r;
      i32x4v lo = *(const i32x4v*)(p + sw0);
      i32x4v hi = *(const i32x4v*)(p + sw1);
      i32x8v b_frag = __builtin_shufflevector(lo, hi, 0, 1, 2, 3, 4, 5, 6, 7);
#pragma unroll
      for (int i = 0; i < 8; ++i)
        acc[i][j] = __builtin_amdgcn_mfma_scale_f32_16x16x128_f8f6f4(
            a_frag[i], b_frag, acc[i][j], 0, 0, 0, SCALE1, 0, SCALE1);
    }
  }
#undef ISSUE_TILE

  // C/D layout (shape-determined): col = lane&15, row = quad*4 + reg.
  // Global row of acc[i][*][r] = m0 + wr*128 + i*16 + quad*4 + r
  float rmax[8][4];
#pragma unroll
  for (int i = 0; i < 8; ++i)
#pragma unroll
    for (int r = 0; r < 4; ++r) {
      float mx = fmaxf(fmaxf(acc[i][0][r], acc[i][1][r]),
                       fmaxf(acc[i][2][r], acc[i][3][r]));
#pragma unroll
      for (int off = 1; off < 16; off <<= 1)
        mx = fmaxf(mx, __shfl_xor(mx, off, 64));
      rmax[i][r] = mx;
    }
  __syncthreads();  // all waves past final ds_reads; sMem safe to alias
  if (lc == 0) {
#pragma unroll
    for (int i = 0; i < 8; ++i)
#pragma unroll
      for (int r = 0; r < 4; ++r)
        maxbuf[(wr * 128 + i * 16 + quad * 4 + r) * 4 + wc] = rmax[i][r];
  }
  __syncthreads();
  float rowmax[8][4];
#pragma unroll
  for (int i = 0; i < 8; ++i)
#pragma unroll
    for (int r = 0; r < 4; ++r) {
      int row = wr * 128 + i * 16 + quad * 4 + r;
      rowmax[i][r] = fmaxf(fmaxf(maxbuf[row * 4], maxbuf[row * 4 + 1]),
                           fmaxf(maxbuf[row * 4 + 2], maxbuf[row * 4 + 3]));
    }
#pragma unroll
  for (int i = 0; i < 8; ++i)
#pragma unroll
    for (int r = 0; r < 4; ++r) {
      float s = __expf(acc[i][0][r] - rowmax[i][r]) + __expf(acc[i][1][r] - rowmax[i][r]) +
                __expf(acc[i][2][r] - rowmax[i][r]) + __expf(acc[i][3][r] - rowmax[i][r]);
#pragma unroll
      for (int off = 1; off < 16; off <<= 1)
        s += __shfl_xor(s, off, 64);
      if (lc == 0) sumbuf[(wr * 128 + i * 16 + quad * 4 + r) * 4 + wc] = s;
    }
  __syncthreads();
  if (wc == 0 && lc == 0) {
#pragma unroll
    for (int i = 0; i < 8; ++i)
#pragma unroll
      for (int r = 0; r < 4; ++r) {
        int row = wr * 128 + i * 16 + quad * 4 + r;
        size_t idx = (size_t)(m0 + row) * CT_NUM + ct;
        m_part[idx] = rowmax[i][r];
        s_part[idx] = sumbuf[row * 4] + sumbuf[row * 4 + 1] +
                      sumbuf[row * 4 + 2] + sumbuf[row * 4 + 3];
      }
  }
}

// ------- combine partials + target logit -> atomic add into out (zeroed) -------
__global__ __launch_bounds__(256) void k_combine(const float* __restrict__ x,
                                                 const unsigned char* __restrict__ wT8,
                                                 const int* __restrict__ target,
                                                 const float* __restrict__ m_part,
                                                 const float* __restrict__ s_part,
                                                 float* __restrict__ out) {
  __shared__ float red[8];
  const int wv = threadIdx.x >> 6;
  const int row = blockIdx.x * 4 + wv;  // one wave per row
  const int l = threadIdx.x & 63;
  float m = -INFINITY, s = 0.f;
  for (int ctb = l; ctb < CT_NUM; ctb += 64) {
    float mj = m_part[(size_t)row * CT_NUM + ctb];
    float sj = s_part[(size_t)row * CT_NUM + ctb];
    float M = fmaxf(m, mj);
    s = s * __expf(m - M) + sj * __expf(mj - M);
    m = M;
  }
#pragma unroll
  for (int off = 1; off < 64; off <<= 1) {
    float mo = __shfl_xor(m, off, 64);
    float so = __shfl_xor(s, off, 64);
    float M = fmaxf(m, mo);
    s = s * __expf(m - M) + so * __expf(mo - M);
    m = M;
  }
  float lse = m + logf(s);
  int tgt = target[row];
  bool valid = (tgt != IGNORE_INDEX);
  int st = valid ? tgt : 0;
  // target logit: x[row] fp32 . wT8[st] fp8 (16 bytes per lane)
  const float* xr = x + (size_t)row * H_DIM + l * 16;
  int4 wv4 = *(const int4*)(wT8 + (size_t)st * H_DIM + l * 16);
  float t = 0.f;
#define ACC_DW(dw, base)                                              \
  t += xr[base + 0] * __builtin_amdgcn_cvt_f32_fp8(dw, 0);            \
  t += xr[base + 1] * __builtin_amdgcn_cvt_f32_fp8(dw, 1);            \
  t += xr[base + 2] * __builtin_amdgcn_cvt_f32_fp8(dw, 2);            \
  t += xr[base + 3] * __builtin_amdgcn_cvt_f32_fp8(dw, 3);
  ACC_DW(wv4.x, 0)
  ACC_DW(wv4.y, 4)
  ACC_DW(wv4.z, 8)
  ACC_DW(wv4.w, 12)
#undef ACC_DW
#pragma unroll
  for (int off = 1; off < 64; off <<= 1)
    t += __shfl_xor(t, off, 64);
  if (l == 0) {
    red[wv * 2]     = valid ? (lse - t) : 0.f;
    red[wv * 2 + 1] = valid ? lse : 0.f;
  }
  __syncthreads();
  if (threadIdx.x == 0) {
    atomicAdd(&out[0], red[0] + red[2] + red[4] + red[6]);
    atomicAdd(&out[1], red[1] + red[3] + red[5] + red[7]);
  }
}

extern "C" void kernel_launch(void* const* d_in, const int* in_sizes, int n_in,
                              void* d_out, int out_size, void* d_ws, size_t ws_size,
                              hipStream_t stream) {
  const float* x = (const float*)d_in[0];
  const float* w = (const float*)d_in[1];
  const int* target = (const int*)d_in[2];
  float* out = (float*)d_out;

  char* ws = (char*)d_ws;
  // ws layout:
  //   x8       : 4096*1024   =  4,194,304
  //   wT8      : 32000*1024  = 32,768,000
  //   m_part   : 4096*125*4  =  2,048,000
  //   s_part   : 4096*125*4  =  2,048,000
  unsigned char* x8 = (unsigned char*)ws;
  unsigned char* wT8 = (unsigned char*)(ws + 4194304);
  float* m_part = (float*)(ws + 4194304 + 32768000);
  float* s_part = (float*)(ws + 4194304 + 32768000 + 2048000);

  hipMemsetAsync(d_out, 0, (size_t)out_size * sizeof(float), stream);
  k_prep<<<dim3(XB8 + (V_DIM / 64) * (H_DIM / 128)), 256, 0, stream>>>(x, w, x8, wT8);
  k_gemm_lse<<<dim3(RT_NUM, CT_NUM), 512, 0, stream>>>(x8, wT8, m_part, s_part);
  k_combine<<<dim3(N_ROWS / 4), 256, 0, stream>>>(x, wT8, target, m_part, s_part, out);
}

// Round 10
// 564.555 us; speedup vs baseline: 1.1359x; 1.1359x over previous
//
#include <hip/hip_runtime.h>
#include <hip/hip_bf16.h>

typedef float f32x4 __attribute__((ext_vector_type(4)));
typedef int i32x4v __attribute__((ext_vector_type(4)));
typedef int i32x8v __attribute__((ext_vector_type(8)));

#define IGNORE_INDEX (-100)
#define N_ROWS 4096
#define H_DIM  1024
#define V_DIM  32000

#define BM 128
#define BN 128
#define BK 128                 /* fp8 elements = bytes */
#define CT_NUM (V_DIM / BN)    /* 250 */
#define RT_NUM (N_ROWS / BM)   /* 32 */
#define SCALE1 0x7f7f7f7f      /* 4x e8m0 = 127 -> x1.0 */

// ---------- fused prep: cast x -> fp8 (blocks < XB8) + transpose-cast w ----------
#define XB8 (N_ROWS * H_DIM / (256 * 16))  /* 1024 */
__global__ __launch_bounds__(256) void k_prep(const float* __restrict__ x,
                                              const float* __restrict__ w,
                                              unsigned char* __restrict__ x8,
                                              unsigned char* __restrict__ wT8) {
  __shared__ float tile[128][65];
  const int t = threadIdx.x;
  if (blockIdx.x < XB8) {
    size_t i = ((size_t)blockIdx.x * 256 + t) * 16;
    const float4* xp = (const float4*)(x + i);
    float4 f0 = xp[0], f1 = xp[1], f2 = xp[2], f3 = xp[3];
    int4 o;
    int r;
    r = __builtin_amdgcn_cvt_pk_fp8_f32(f0.x, f0.y, 0, false);
    r = __builtin_amdgcn_cvt_pk_fp8_f32(f0.z, f0.w, r, true);
    o.x = r;
    r = __builtin_amdgcn_cvt_pk_fp8_f32(f1.x, f1.y, 0, false);
    r = __builtin_amdgcn_cvt_pk_fp8_f32(f1.z, f1.w, r, true);
    o.y = r;
    r = __builtin_amdgcn_cvt_pk_fp8_f32(f2.x, f2.y, 0, false);
    r = __builtin_amdgcn_cvt_pk_fp8_f32(f2.z, f2.w, r, true);
    o.z = r;
    r = __builtin_amdgcn_cvt_pk_fp8_f32(f3.x, f3.y, 0, false);
    r = __builtin_amdgcn_cvt_pk_fp8_f32(f3.z, f3.w, r, true);
    o.w = r;
    *(int4*)(x8 + i) = o;
    return;
  }
  const int b = blockIdx.x - XB8;
  const int v0 = (b % (V_DIM / 64)) * 64;
  const int k0 = (b / (V_DIM / 64)) * 128;
  {
    const int vq = t & 15;    // float4 index (16 x 4 = 64 floats/row)
    const int kr = t >> 4;    // 0..15
#pragma unroll
    for (int p = 0; p < 128; p += 16) {
      float4 v = *(const float4*)(w + (size_t)(k0 + kr + p) * V_DIM + v0 + vq * 4);
      tile[kr + p][vq * 4 + 0] = v.x;
      tile[kr + p][vq * 4 + 1] = v.y;
      tile[kr + p][vq * 4 + 2] = v.z;
      tile[kr + p][vq * 4 + 3] = v.w;
    }
  }
  __syncthreads();
  {
    const int vr = t >> 2;    // 0..63
    const int kq2 = t & 3;
#pragma unroll
    for (int h = 0; h < 2; ++h) {
      const int d4 = kq2 + h * 4;   // int4 index within 128B k-run
      int4 o;
      int r;
#pragma unroll
      for (int d = 0; d < 4; ++d) {
        r = __builtin_amdgcn_cvt_pk_fp8_f32(tile[d4 * 16 + d * 4 + 0][vr],
                                            tile[d4 * 16 + d * 4 + 1][vr], 0, false);
        r = __builtin_amdgcn_cvt_pk_fp8_f32(tile[d4 * 16 + d * 4 + 2][vr],
                                            tile[d4 * 16 + d * 4 + 3][vr], r, true);
        ((int*)&o)[d] = r;
      }
      *(int4*)(wT8 + (size_t)(v0 + vr) * H_DIM + k0 + d4 * 16) = o;
    }
  }
}

// --- fused MX-fp8 GEMM (128x128, 4 waves) + lse; A via LDS dbuf, B DIRECT ---
// R7 analysis: 64x64 wave-tile reads 1 KB LDS per MFMA = 8 cyc/MFMA at
// 128 B/cyc — co-equal with the 8.6 cyc MFMA pipe, plus 32 KB/iter of
// barrier-coupled staging. Fix: B fragments load straight from global
// (wT8 rows contiguous; per-wave lo/hi instruction pair covers 16 full
// 128B lines). Halves LDS reads AND barrier-coupled staging; B loads are
// plain VMEM, overlappable across waves, not drained as aged-DMA.
// Issue order per iter: b-loads FIRST, then ISSUE_A(kt+1) — vmcnt is FIFO,
// so waiting on b leaves the staging DMA in flight across the compute phase.
// Regs ~R7's 124 + ~6 addr => ~130; no launch-bounds min-waves (R5 lesson).
__global__ __launch_bounds__(256) void k_gemm_lse(const unsigned char* __restrict__ A,
                                                  const unsigned char* __restrict__ Bt,
                                                  float* __restrict__ m_part,
                                                  float* __restrict__ s_part) {
  __shared__ __align__(16) unsigned char sA[2][BM * BK];   // A double-buffer only
  float* maxbuf = (float*)&sA[0][0];            // [BM][2], alias post-loop
  float* sumbuf = (float*)&sA[0][2048];         // [BM][2]

  const int tid = threadIdx.x;
  const int rt = blockIdx.x;   // fast dim -> per-XCD A stays hot
  const int ct = blockIdx.y;
  const int m0 = rt * BM;
  const int n0 = ct * BN;

  const int w = tid >> 6;
  const int l = tid & 63;
  const int wr = w >> 1, wc = w & 1;
  const int quad = l >> 4, lc = l & 15;

  f32x4 acc[4][4];
#pragma unroll
  for (int i = 0; i < 4; ++i)
#pragma unroll
    for (int j = 0; j < 4; ++j)
      acc[i][j] = (f32x4){0.f, 0.f, 0.f, 0.f};

  // A staging (16 KB/tile): slot s = issue*256+tid; row = s>>3,
  // chunk-pos (s&7) = c ^ (row&7) (XOR swizzle, conflict-managed reads).
  const int srow = tid >> 3;                               // 0..31
  const int scol = ((tid & 7) ^ ((tid >> 3) & 7)) * 16;    // swizzled 16B chunk
  const unsigned char* ga = A + (size_t)(m0 + srow) * H_DIM + scol;
  const int dOff = tid * 16;

  // A fragment read offsets
  const int base_r = lc * 128;
  const int sw0 = ((quad * 2) ^ (lc & 7)) * 16;
  const int sw1 = ((quad * 2 + 1) ^ (lc & 7)) * 16;

  // B direct-from-global base: row = n0 + wc*64 + j*16 + lc, bytes quad*32..
  const unsigned char* gb = Bt + (size_t)(n0 + wc * 64 + lc) * H_DIM + quad * 32;

#define ISSUE_A(buf)                                                             \
  do {                                                                           \
    unsigned char* da_ = &sA[buf][dOff];                                         \
    _Pragma("unroll")                                                            \
    for (int i_ = 0; i_ < 4; ++i_) {                                             \
      __builtin_amdgcn_global_load_lds(                                          \
          (const __attribute__((address_space(1))) void*)(ga + (size_t)i_ * 32 * H_DIM), \
          (__attribute__((address_space(3))) void*)(da_ + i_ * 4096), 16, 0, 0); \
    }                                                                            \
    ga += BK;                                                                    \
  } while (0)

  ISSUE_A(0);  // cold prologue load, tile 0

#pragma unroll
  for (int kt = 0; kt < H_DIM / BK; ++kt) {
    __syncthreads();  // drains tile-kt A staging (aged 1 compute phase for kt>0);
                      // guarantees all waves done reading sA[(kt+1)&1]

    // B fragments: 8 global dwordx4 loads, issued BEFORE next staging so the
    // vmcnt wait for b leaves the staging DMA outstanding.
    i32x8v b_frag[4];
#pragma unroll
    for (int j = 0; j < 4; ++j) {
      const unsigned char* p = gb + (size_t)j * 16 * H_DIM + kt * BK;
      i32x4v lo = *(const i32x4v*)(p);
      i32x4v hi = *(const i32x4v*)(p + 16);
      b_frag[j] = __builtin_shufflevector(lo, hi, 0, 1, 2, 3, 4, 5, 6, 7);
    }

    if (kt < H_DIM / BK - 1) ISSUE_A((kt + 1) & 1);

    const unsigned char* bufA = &sA[kt & 1][0];
    i32x8v a_frag[4];
#pragma unroll
    for (int i = 0; i < 4; ++i) {
      const unsigned char* p = bufA + (wr * 4 + i) * 2048 + base_r;
      i32x4v lo = *(const i32x4v*)(p + sw0);
      i32x4v hi = *(const i32x4v*)(p + sw1);
      a_frag[i] = __builtin_shufflevector(lo, hi, 0, 1, 2, 3, 4, 5, 6, 7);
    }
#pragma unroll
    for (int i = 0; i < 4; ++i)
#pragma unroll
      for (int j = 0; j < 4; ++j)
        acc[i][j] = __builtin_amdgcn_mfma_scale_f32_16x16x128_f8f6f4(
            a_frag[i], b_frag[j], acc[i][j], 0, 0, 0, SCALE1, 0, SCALE1);
  }
#undef ISSUE_A

  // C/D layout (shape-determined): col = lane&15, row = quad*4 + reg.
  // Global row of acc[i][*][r] = m0 + wr*64 + i*16 + quad*4 + r
  float rmax[4][4];
#pragma unroll
  for (int i = 0; i < 4; ++i)
#pragma unroll
    for (int r = 0; r < 4; ++r) {
      float mx = fmaxf(fmaxf(acc[i][0][r], acc[i][1][r]),
                       fmaxf(acc[i][2][r], acc[i][3][r]));
#pragma unroll
      for (int off = 1; off < 16; off <<= 1)
        mx = fmaxf(mx, __shfl_xor(mx, off, 64));
      rmax[i][r] = mx;
    }
  __syncthreads();  // all waves past final ds_reads; sA safe to alias
  if (lc == 0) {
#pragma unroll
    for (int i = 0; i < 4; ++i)
#pragma unroll
      for (int r = 0; r < 4; ++r)
        maxbuf[(wr * 64 + i * 16 + quad * 4 + r) * 2 + wc] = rmax[i][r];
  }
  __syncthreads();
  float rowmax[4][4];
#pragma unroll
  for (int i = 0; i < 4; ++i)
#pragma unroll
    for (int r = 0; r < 4; ++r) {
      int row = wr * 64 + i * 16 + quad * 4 + r;
      rowmax[i][r] = fmaxf(maxbuf[row * 2], maxbuf[row * 2 + 1]);
    }
#pragma unroll
  for (int i = 0; i < 4; ++i)
#pragma unroll
    for (int r = 0; r < 4; ++r) {
      float s = __expf(acc[i][0][r] - rowmax[i][r]) + __expf(acc[i][1][r] - rowmax[i][r]) +
                __expf(acc[i][2][r] - rowmax[i][r]) + __expf(acc[i][3][r] - rowmax[i][r]);
#pragma unroll
      for (int off = 1; off < 16; off <<= 1)
        s += __shfl_xor(s, off, 64);
      if (lc == 0) sumbuf[(wr * 64 + i * 16 + quad * 4 + r) * 2 + wc] = s;
    }
  __syncthreads();
  if (wc == 0 && lc == 0) {
#pragma unroll
    for (int i = 0; i < 4; ++i)
#pragma unroll
      for (int r = 0; r < 4; ++r) {
        int row = wr * 64 + i * 16 + quad * 4 + r;
        size_t idx = (size_t)(m0 + row) * CT_NUM + ct;
        m_part[idx] = rowmax[i][r];
        s_part[idx] = sumbuf[row * 2] + sumbuf[row * 2 + 1];
      }
  }
}

// ------- combine partials + target logit -> atomic add into out (zeroed) -------
__global__ __launch_bounds__(256) void k_combine(const float* __restrict__ x,
                                                 const unsigned char* __restrict__ wT8,
                                                 const int* __restrict__ target,
                                                 const float* __restrict__ m_part,
                                                 const float* __restrict__ s_part,
                                                 float* __restrict__ out) {
  __shared__ float red[8];
  const int wv = threadIdx.x >> 6;
  const int row = blockIdx.x * 4 + wv;  // one wave per row
  const int l = threadIdx.x & 63;
  float m = -INFINITY, s = 0.f;
  for (int ctb = l; ctb < CT_NUM; ctb += 64) {
    float mj = m_part[(size_t)row * CT_NUM + ctb];
    float sj = s_part[(size_t)row * CT_NUM + ctb];
    float M = fmaxf(m, mj);
    s = s * __expf(m - M) + sj * __expf(mj - M);
    m = M;
  }
#pragma unroll
  for (int off = 1; off < 64; off <<= 1) {
    float mo = __shfl_xor(m, off, 64);
    float so = __shfl_xor(s, off, 64);
    float M = fmaxf(m, mo);
    s = s * __expf(m - M) + so * __expf(mo - M);
    m = M;
  }
  float lse = m + logf(s);
  int tgt = target[row];
  bool valid = (tgt != IGNORE_INDEX);
  int st = valid ? tgt : 0;
  // target logit: x[row] fp32 . wT8[st] fp8 (16 bytes per lane)
  const float* xr = x + (size_t)row * H_DIM + l * 16;
  int4 wv4 = *(const int4*)(wT8 + (size_t)st * H_DIM + l * 16);
  float t = 0.f;
#define ACC_DW(dw, base)                                              \
  t += xr[base + 0] * __builtin_amdgcn_cvt_f32_fp8(dw, 0);            \
  t += xr[base + 1] * __builtin_amdgcn_cvt_f32_fp8(dw, 1);            \
  t += xr[base + 2] * __builtin_amdgcn_cvt_f32_fp8(dw, 2);            \
  t += xr[base + 3] * __builtin_amdgcn_cvt_f32_fp8(dw, 3);
  ACC_DW(wv4.x, 0)
  ACC_DW(wv4.y, 4)
  ACC_DW(wv4.z, 8)
  ACC_DW(wv4.w, 12)
#undef ACC_DW
#pragma unroll
  for (int off = 1; off < 64; off <<= 1)
    t += __shfl_xor(t, off, 64);
  if (l == 0) {
    red[wv * 2]     = valid ? (lse - t) : 0.f;
    red[wv * 2 + 1] = valid ? lse : 0.f;
  }
  __syncthreads();
  if (threadIdx.x == 0) {
    atomicAdd(&out[0], red[0] + red[2] + red[4] + red[6]);
    atomicAdd(&out[1], red[1] + red[3] + red[5] + red[7]);
  }
}

extern "C" void kernel_launch(void* const* d_in, const int* in_sizes, int n_in,
                              void* d_out, int out_size, void* d_ws, size_t ws_size,
                              hipStream_t stream) {
  const float* x = (const float*)d_in[0];
  const float* w = (const float*)d_in[1];
  const int* target = (const int*)d_in[2];
  float* out = (float*)d_out;

  char* ws = (char*)d_ws;
  // ws layout:
  //   x8       : 4096*1024   =  4,194,304
  //   wT8      : 32000*1024  = 32,768,000
  //   m_part   : 4096*250*4  =  4,096,000
  //   s_part   : 4096*250*4  =  4,096,000
  unsigned char* x8 = (unsigned char*)ws;
  unsigned char* wT8 = (unsigned char*)(ws + 4194304);
  float* m_part = (float*)(ws + 4194304 + 32768000);
  float* s_part = (float*)(ws + 4194304 + 32768000 + 4096000);

  hipMemsetAsync(d_out, 0, (size_t)out_size * sizeof(float), stream);
  k_prep<<<dim3(XB8 + (V_DIM / 64) * (H_DIM / 128)), 256, 0, stream>>>(x, w, x8, wT8);
  k_gemm_lse<<<dim3(RT_NUM, CT_NUM), 256, 0, stream>>>(x8, wT8, m_part, s_part);
  k_combine<<<dim3(N_ROWS / 4), 256, 0, stream>>>(x, wT8, target, m_part, s_part, out);
}

// Round 11
// 440.306 us; speedup vs baseline: 1.4564x; 1.2822x over previous
//
#include <hip/hip_runtime.h>
#include <hip/hip_bf16.h>

typedef float f32x4 __attribute__((ext_vector_type(4)));
typedef int i32x4v __attribute__((ext_vector_type(4)));
typedef int i32x8v __attribute__((ext_vector_type(8)));

#define IGNORE_INDEX (-100)
#define N_ROWS 4096
#define H_DIM  1024
#define V_DIM  32000

#define BM 128
#define BN 128
#define BK 128                 /* fp8 elements = bytes */
#define CT_NUM (V_DIM / BN)    /* 250 */
#define RT_NUM (N_ROWS / BM)   /* 32 */
#define SCALE1 0x7f7f7f7f      /* 4x e8m0 = 127 -> x1.0 */

// x8s fragment-major layout: [panel(64)][kt(8)][i(4)][h(2)][lane(64)][16B]
//   row  = panel*64 + i*16 + lc   (lc = lane&15)
//   k    = kt*128 + (lane>>4)*32 + h*16 + (byte 0..15)
// A wave's a_frag[i] load = two perfectly-contiguous 1KB global reads.
#define X8S_OFF(panel, kt, i, h) \
  ((((size_t)(panel) * 8 + (kt)) * 4 + (i)) * 2 + (h)) * 1024

// ---------- fused prep: cast x -> fragment-major fp8 + transpose-cast w ----------
#define XB8 (N_ROWS * H_DIM / (256 * 16))  /* 1024 */
__global__ __launch_bounds__(256) void k_prep(const float* __restrict__ x,
                                              const float* __restrict__ w,
                                              unsigned char* __restrict__ x8s,
                                              unsigned char* __restrict__ wT8) {
  __shared__ float tile[128][65];
  const int t = threadIdx.x;
  if (blockIdx.x < XB8) {
    // each thread: 16 consecutive k of one row -> exactly one 16B slot of x8s
    const int f = blockIdx.x * 256 + t;
    const int row = f >> 6;
    const int k0 = (f & 63) * 16;
    const float4* xp = (const float4*)(x + (size_t)row * H_DIM + k0);
    float4 f0 = xp[0], f1 = xp[1], f2 = xp[2], f3 = xp[3];
    int4 o;
    int r;
    r = __builtin_amdgcn_cvt_pk_fp8_f32(f0.x, f0.y, 0, false);
    r = __builtin_amdgcn_cvt_pk_fp8_f32(f0.z, f0.w, r, true);
    o.x = r;
    r = __builtin_amdgcn_cvt_pk_fp8_f32(f1.x, f1.y, 0, false);
    r = __builtin_amdgcn_cvt_pk_fp8_f32(f1.z, f1.w, r, true);
    o.y = r;
    r = __builtin_amdgcn_cvt_pk_fp8_f32(f2.x, f2.y, 0, false);
    r = __builtin_amdgcn_cvt_pk_fp8_f32(f2.z, f2.w, r, true);
    o.z = r;
    r = __builtin_amdgcn_cvt_pk_fp8_f32(f3.x, f3.y, 0, false);
    r = __builtin_amdgcn_cvt_pk_fp8_f32(f3.z, f3.w, r, true);
    o.w = r;
    const int panel = row >> 6, i = (row >> 4) & 3, lc = row & 15;
    const int kt = k0 >> 7, kb = k0 & 127;
    const int q = kb >> 5, h = (kb >> 4) & 1;
    const int lane = q * 16 + lc;
    *(int4*)(x8s + X8S_OFF(panel, kt, i, h) + lane * 16) = o;
    return;
  }
  const int b = blockIdx.x - XB8;
  const int v0 = (b % (V_DIM / 64)) * 64;
  const int k0 = (b / (V_DIM / 64)) * 128;
  {
    const int vq = t & 15;    // float4 index (16 x 4 = 64 floats/row)
    const int kr = t >> 4;    // 0..15
#pragma unroll
    for (int p = 0; p < 128; p += 16) {
      float4 v = *(const float4*)(w + (size_t)(k0 + kr + p) * V_DIM + v0 + vq * 4);
      tile[kr + p][vq * 4 + 0] = v.x;
      tile[kr + p][vq * 4 + 1] = v.y;
      tile[kr + p][vq * 4 + 2] = v.z;
      tile[kr + p][vq * 4 + 3] = v.w;
    }
  }
  __syncthreads();
  {
    const int vr = t >> 2;    // 0..63
    const int kq2 = t & 3;
#pragma unroll
    for (int h = 0; h < 2; ++h) {
      const int d4 = kq2 + h * 4;   // int4 index within 128B k-run
      int4 o;
      int r;
#pragma unroll
      for (int d = 0; d < 4; ++d) {
        r = __builtin_amdgcn_cvt_pk_fp8_f32(tile[d4 * 16 + d * 4 + 0][vr],
                                            tile[d4 * 16 + d * 4 + 1][vr], 0, false);
        r = __builtin_amdgcn_cvt_pk_fp8_f32(tile[d4 * 16 + d * 4 + 2][vr],
                                            tile[d4 * 16 + d * 4 + 3][vr], r, true);
        ((int*)&o)[d] = r;
      }
      *(int4*)(wT8 + (size_t)(v0 + vr) * H_DIM + k0 + d4 * 16) = o;
    }
  }
}

// -- fused MX-fp8 GEMM (128x128, 4 waves): A DIRECT from fragment-major x8s,
//    B staged via aged-prefetch LDS dbuf.  R7 budget was LDS 1536 cyc/CU-iter
//    (reads 1024 + DMA 512) vs MFMA 1100 — LDS-bound.  Removing A from LDS:
//    LDS = 768 cyc < MFMA 1100 -> MFMA-bound.  A-loads are contiguous 1KB
//    wave-reads of an L2-hot 32KB panel (reused by 125 ct blocks).
//    Issue order: ISSUE_B(kt+1) first, then a-loads(kt): MFMA's vmcnt wait
//    leaves the B-DMA in flight; barrier drains it one compute phase later.
__global__ __launch_bounds__(256) void k_gemm_lse(const unsigned char* __restrict__ x8s,
                                                  const unsigned char* __restrict__ Bt,
                                                  float* __restrict__ m_part,
                                                  float* __restrict__ s_part) {
  __shared__ __align__(16) unsigned char sB[2][BN * BK];   // B double-buffer only
  float* maxbuf = (float*)&sB[0][0];            // [BM][2], alias post-loop
  float* sumbuf = (float*)&sB[0][2048];         // [BM][2]

  const int tid = threadIdx.x;
  const int rt = blockIdx.x;   // fast dim -> per-XCD A stays hot
  const int ct = blockIdx.y;
  const int m0 = rt * BM;
  const int n0 = ct * BN;

  const int w = tid >> 6;
  const int l = tid & 63;
  const int wr = w >> 1, wc = w & 1;
  const int quad = l >> 4, lc = l & 15;

  f32x4 acc[4][4];
#pragma unroll
  for (int i = 0; i < 4; ++i)
#pragma unroll
    for (int j = 0; j < 4; ++j)
      acc[i][j] = (f32x4){0.f, 0.f, 0.f, 0.f};

  // B staging (16 KB/tile): slot s = issue*256+tid; row = s>>3,
  // chunk-pos (s&7) = c ^ (row&7) (XOR swizzle).
  const int srow = tid >> 3;                               // 0..31
  const int scol = ((tid & 7) ^ ((tid >> 3) & 7)) * 16;    // swizzled 16B chunk
  const unsigned char* gb = Bt + (size_t)(n0 + srow) * H_DIM + scol;
  const int dOff = tid * 16;

  // B fragment read offsets
  const int base_r = lc * 128;
  const int sw0 = ((quad * 2) ^ (lc & 7)) * 16;
  const int sw1 = ((quad * 2 + 1) ^ (lc & 7)) * 16;

  // A direct: per-wave panel base (fragment-major)
  const unsigned char* pa = x8s + X8S_OFF(rt * 2 + wr, 0, 0, 0) + l * 16;

#define ISSUE_B(buf)                                                             \
  do {                                                                           \
    unsigned char* db_ = &sB[buf][dOff];                                         \
    _Pragma("unroll")                                                            \
    for (int i_ = 0; i_ < 4; ++i_) {                                             \
      __builtin_amdgcn_global_load_lds(                                          \
          (const __attribute__((address_space(1))) void*)(gb + (size_t)i_ * 32 * H_DIM), \
          (__attribute__((address_space(3))) void*)(db_ + i_ * 4096), 16, 0, 0); \
    }                                                                            \
    gb += BK;                                                                    \
  } while (0)

  ISSUE_B(0);  // cold prologue load, tile 0

#pragma unroll
  for (int kt = 0; kt < H_DIM / BK; ++kt) {
    __syncthreads();  // drains B-DMA(kt) (aged 1 compute phase for kt>0);
                      // guarantees all waves done reading sB[(kt+1)&1]
    if (kt < H_DIM / BK - 1) ISSUE_B((kt + 1) & 1);

    // A fragments direct from global (contiguous 1KB per wave per load)
    i32x8v a_frag[4];
#pragma unroll
    for (int i = 0; i < 4; ++i) {
      const unsigned char* p = pa + (size_t)kt * 8192 + i * 2048;
      i32x4v lo = *(const i32x4v*)(p);
      i32x4v hi = *(const i32x4v*)(p + 1024);
      a_frag[i] = __builtin_shufflevector(lo, hi, 0, 1, 2, 3, 4, 5, 6, 7);
    }

    const unsigned char* bufB = &sB[kt & 1][0];
    i32x8v b_frag[4];
#pragma unroll
    for (int j = 0; j < 4; ++j) {
      const unsigned char* p = bufB + (wc * 4 + j) * 2048 + base_r;
      i32x4v lo = *(const i32x4v*)(p + sw0);
      i32x4v hi = *(const i32x4v*)(p + sw1);
      b_frag[j] = __builtin_shufflevector(lo, hi, 0, 1, 2, 3, 4, 5, 6, 7);
    }
#pragma unroll
    for (int i = 0; i < 4; ++i)
#pragma unroll
      for (int j = 0; j < 4; ++j)
        acc[i][j] = __builtin_amdgcn_mfma_scale_f32_16x16x128_f8f6f4(
            a_frag[i], b_frag[j], acc[i][j], 0, 0, 0, SCALE1, 0, SCALE1);
  }
#undef ISSUE_B

  // C/D layout (shape-determined): col = lane&15, row = quad*4 + reg.
  // Global row of acc[i][*][r] = m0 + wr*64 + i*16 + quad*4 + r
  float rmax[4][4];
#pragma unroll
  for (int i = 0; i < 4; ++i)
#pragma unroll
    for (int r = 0; r < 4; ++r) {
      float mx = fmaxf(fmaxf(acc[i][0][r], acc[i][1][r]),
                       fmaxf(acc[i][2][r], acc[i][3][r]));
#pragma unroll
      for (int off = 1; off < 16; off <<= 1)
        mx = fmaxf(mx, __shfl_xor(mx, off, 64));
      rmax[i][r] = mx;
    }
  __syncthreads();  // all waves past final ds_reads; sB safe to alias
  if (lc == 0) {
#pragma unroll
    for (int i = 0; i < 4; ++i)
#pragma unroll
      for (int r = 0; r < 4; ++r)
        maxbuf[(wr * 64 + i * 16 + quad * 4 + r) * 2 + wc] = rmax[i][r];
  }
  __syncthreads();
  float rowmax[4][4];
#pragma unroll
  for (int i = 0; i < 4; ++i)
#pragma unroll
    for (int r = 0; r < 4; ++r) {
      int row = wr * 64 + i * 16 + quad * 4 + r;
      rowmax[i][r] = fmaxf(maxbuf[row * 2], maxbuf[row * 2 + 1]);
    }
#pragma unroll
  for (int i = 0; i < 4; ++i)
#pragma unroll
    for (int r = 0; r < 4; ++r) {
      float s = __expf(acc[i][0][r] - rowmax[i][r]) + __expf(acc[i][1][r] - rowmax[i][r]) +
                __expf(acc[i][2][r] - rowmax[i][r]) + __expf(acc[i][3][r] - rowmax[i][r]);
#pragma unroll
      for (int off = 1; off < 16; off <<= 1)
        s += __shfl_xor(s, off, 64);
      if (lc == 0) sumbuf[(wr * 64 + i * 16 + quad * 4 + r) * 2 + wc] = s;
    }
  __syncthreads();
  if (wc == 0 && lc == 0) {
#pragma unroll
    for (int i = 0; i < 4; ++i)
#pragma unroll
      for (int r = 0; r < 4; ++r) {
        int row = wr * 64 + i * 16 + quad * 4 + r;
        size_t idx = (size_t)(m0 + row) * CT_NUM + ct;
        m_part[idx] = rowmax[i][r];
        s_part[idx] = sumbuf[row * 2] + sumbuf[row * 2 + 1];
      }
  }
}

// ------- combine partials + target logit -> atomic add into out (zeroed) -------
__global__ __launch_bounds__(256) void k_combine(const float* __restrict__ x,
                                                 const unsigned char* __restrict__ wT8,
                                                 const int* __restrict__ target,
                                                 const float* __restrict__ m_part,
                                                 const float* __restrict__ s_part,
                                                 float* __restrict__ out) {
  __shared__ float red[8];
  const int wv = threadIdx.x >> 6;
  const int row = blockIdx.x * 4 + wv;  // one wave per row
  const int l = threadIdx.x & 63;
  float m = -INFINITY, s = 0.f;
  for (int ctb = l; ctb < CT_NUM; ctb += 64) {
    float mj = m_part[(size_t)row * CT_NUM + ctb];
    float sj = s_part[(size_t)row * CT_NUM + ctb];
    float M = fmaxf(m, mj);
    s = s * __expf(m - M) + sj * __expf(mj - M);
    m = M;
  }
#pragma unroll
  for (int off = 1; off < 64; off <<= 1) {
    float mo = __shfl_xor(m, off, 64);
    float so = __shfl_xor(s, off, 64);
    float M = fmaxf(m, mo);
    s = s * __expf(m - M) + so * __expf(mo - M);
    m = M;
  }
  float lse = m + logf(s);
  int tgt = target[row];
  bool valid = (tgt != IGNORE_INDEX);
  int st = valid ? tgt : 0;
  // target logit: x[row] fp32 . wT8[st] fp8 (16 bytes per lane)
  const float* xr = x + (size_t)row * H_DIM + l * 16;
  int4 wv4 = *(const int4*)(wT8 + (size_t)st * H_DIM + l * 16);
  float t = 0.f;
#define ACC_DW(dw, base)                                              \
  t += xr[base + 0] * __builtin_amdgcn_cvt_f32_fp8(dw, 0);            \
  t += xr[base + 1] * __builtin_amdgcn_cvt_f32_fp8(dw, 1);            \
  t += xr[base + 2] * __builtin_amdgcn_cvt_f32_fp8(dw, 2);            \
  t += xr[base + 3] * __builtin_amdgcn_cvt_f32_fp8(dw, 3);
  ACC_DW(wv4.x, 0)
  ACC_DW(wv4.y, 4)
  ACC_DW(wv4.z, 8)
  ACC_DW(wv4.w, 12)
#undef ACC_DW
#pragma unroll
  for (int off = 1; off < 64; off <<= 1)
    t += __shfl_xor(t, off, 64);
  if (l == 0) {
    red[wv * 2]     = valid ? (lse - t) : 0.f;
    red[wv * 2 + 1] = valid ? lse : 0.f;
  }
  __syncthreads();
  if (threadIdx.x == 0) {
    atomicAdd(&out[0], red[0] + red[2] + red[4] + red[6]);
    atomicAdd(&out[1], red[1] + red[3] + red[5] + red[7]);
  }
}

extern "C" void kernel_launch(void* const* d_in, const int* in_sizes, int n_in,
                              void* d_out, int out_size, void* d_ws, size_t ws_size,
                              hipStream_t stream) {
  const float* x = (const float*)d_in[0];
  const float* w = (const float*)d_in[1];
  const int* target = (const int*)d_in[2];
  float* out = (float*)d_out;

  char* ws = (char*)d_ws;
  // ws layout:
  //   x8s      : 4096*1024   =  4,194,304  (fragment-major)
  //   wT8      : 32000*1024  = 32,768,000
  //   m_part   : 4096*250*4  =  4,096,000
  //   s_part   : 4096*250*4  =  4,096,000
  unsigned char* x8s = (unsigned char*)ws;
  unsigned char* wT8 = (unsigned char*)(ws + 4194304);
  float* m_part = (float*)(ws + 4194304 + 32768000);
  float* s_part = (float*)(ws + 4194304 + 32768000 + 4096000);

  hipMemsetAsync(d_out, 0, (size_t)out_size * sizeof(float), stream);
  k_prep<<<dim3(XB8 + (V_DIM / 64) * (H_DIM / 128)), 256, 0, stream>>>(x, w, x8s, wT8);
  k_gemm_lse<<<dim3(RT_NUM, CT_NUM), 256, 0, stream>>>(x8s, wT8, m_part, s_part);
  k_combine<<<dim3(N_ROWS / 4), 256, 0, stream>>>(x, wT8, target, m_part, s_part, out);
}